// Round 1
// baseline (716.258 us; speedup 1.0000x reference)
//
#include <hip/hip_runtime.h>
#include <hip/hip_bf16.h>
#include <stdint.h>

#define NB 8
#define NC 512
#define NN 4096
#define ND 64

typedef __attribute__((ext_vector_type(8))) short short8;
typedef __attribute__((ext_vector_type(4))) float f32x4;

#define LOG2E 1.44269504088896340736f

static __device__ __forceinline__ unsigned short f2bf(float f) {
    union { float f; uint32_t u; } v; v.f = f;
    return (unsigned short)((v.u + 0x7fffu + ((v.u >> 16) & 1u)) >> 16);
}

// ---------------- Kernel A: fused QKV projection (per-batch GEMM) ----------
// Y[o][n] = sum_c W[o][c] * X[c][n] + bias[o]
// o in [0,64): q  -> QT[b][n][o]      (bf16, [B][N][64])
// o in [64,128): k -> KT[b][n][o-64]  (bf16, [B][N][64])
// o in [128,640): v -> V[b][o-128][n] (bf16, [B][512][N])
__global__ __launch_bounds__(256) void qkv_proj(
    const float* __restrict__ x,
    const float* __restrict__ wq, const float* __restrict__ bq,
    const float* __restrict__ wk, const float* __restrict__ bk,
    const float* __restrict__ wv, const float* __restrict__ bv,
    unsigned short* __restrict__ QT, unsigned short* __restrict__ KT,
    unsigned short* __restrict__ V)
{
    const int nblk = blockIdx.x;   // 64 n-tiles of 64
    const int mblk = blockIdx.y;   // 5 m-tiles of 128
    const int b    = blockIdx.z;   // 8 batches
    const int t = threadIdx.x;
    const int wid = t >> 6;
    const int l = t & 63;
    const int lg = l >> 4, lr = l & 15;

    const int o0 = mblk * 128;
    const int n0 = nblk * 64;
    const float* xb = x + (size_t)b * NC * NN;

    // +8 pad: row stride 144B -> 16B-aligned b128 reads, ~2-way banks
    __shared__ unsigned short Wlds[128][72];
    __shared__ unsigned short XT[64][72];   // X tile stored transposed [n][c]

    f32x4 acc[2][4];
    #pragma unroll
    for (int mt = 0; mt < 2; ++mt) {
        #pragma unroll
        for (int bb = 0; bb < 4; ++bb) {
            int o = o0 + wid*32 + mt*16 + lg*4 + bb;
            float bias = (o < 64) ? bq[o] : (o < 128) ? bk[o-64] : bv[o-128];
            #pragma unroll
            for (int nt = 0; nt < 4; ++nt) acc[mt][nt][bb] = bias;
        }
    }

    for (int ks = 0; ks < 8; ++ks) {
        const int c0 = ks * 64;
        __syncthreads();                       // protect prev frag reads
        // stage W tile [128 o][64 c] fp32 -> bf16
        #pragma unroll
        for (int p = 0; p < 8; ++p) {
            int id = t + 256*p;
            int ol = id >> 4;
            int c4 = (id & 15) << 2;
            int o  = o0 + ol;
            const float* wr = (o < 64) ? (wq + (size_t)o*NC)
                           : (o < 128) ? (wk + (size_t)(o-64)*NC)
                                       : (wv + (size_t)(o-128)*NC);
            float4 w4 = *reinterpret_cast<const float4*>(wr + c0 + c4);
            uint2 pk;
            pk.x = (uint32_t)f2bf(w4.x) | ((uint32_t)f2bf(w4.y) << 16);
            pk.y = (uint32_t)f2bf(w4.z) | ((uint32_t)f2bf(w4.w) << 16);
            *reinterpret_cast<uint2*>(&Wlds[ol][c4]) = pk;
        }
        // stage X tile [64 c][64 n], transposed into XT[n][c]
        #pragma unroll
        for (int p = 0; p < 4; ++p) {
            int id = t + 256*p;
            int cl = id >> 4;
            int n4 = (id & 15) << 2;
            float4 x4 = *reinterpret_cast<const float4*>(xb + (size_t)(c0 + cl)*NN + n0 + n4);
            XT[n4+0][cl] = f2bf(x4.x);
            XT[n4+1][cl] = f2bf(x4.y);
            XT[n4+2][cl] = f2bf(x4.z);
            XT[n4+3][cl] = f2bf(x4.w);
        }
        __syncthreads();
        #pragma unroll
        for (int k2 = 0; k2 < 2; ++k2) {
            short8 af[2], bf[4];
            #pragma unroll
            for (int mt = 0; mt < 2; ++mt)
                af[mt] = *reinterpret_cast<const short8*>(&Wlds[wid*32 + mt*16 + lr][k2*32 + lg*8]);
            #pragma unroll
            for (int nt = 0; nt < 4; ++nt)
                bf[nt] = *reinterpret_cast<const short8*>(&XT[nt*16 + lr][k2*32 + lg*8]);
            #pragma unroll
            for (int mt = 0; mt < 2; ++mt)
                #pragma unroll
                for (int nt = 0; nt < 4; ++nt)
                    acc[mt][nt] = __builtin_amdgcn_mfma_f32_16x16x32_bf16(af[mt], bf[nt], acc[mt][nt], 0, 0, 0);
        }
    }

    // epilogue: D layout col n = lr (+16*nt), row o = 4*lg+bb (+16*mt+32*wid)
    #pragma unroll
    for (int mt = 0; mt < 2; ++mt) {
        #pragma unroll
        for (int nt = 0; nt < 4; ++nt) {
            int n = n0 + nt*16 + lr;
            #pragma unroll
            for (int bb = 0; bb < 4; ++bb) {
                int o = o0 + wid*32 + mt*16 + lg*4 + bb;
                unsigned short hb = f2bf(acc[mt][nt][bb]);
                if (o < 64)       QT[((size_t)b*NN + n)*ND + o] = hb;
                else if (o < 128) KT[((size_t)b*NN + n)*ND + (o-64)] = hb;
                else              V[((size_t)b*NC + (o-128))*NN + n] = hb;
            }
        }
    }
}

// ---------------- Kernel B: fused flash attention + residual ----------------
// per block: batch b, 32 queries. 4 waves; wave w owns c-slice [128w,128w+128).
// S^T = K_tile(64s x 64d) * Q_tile^T: wave w computes s-rows [16w,16w+16).
// online softmax across s-tiles; P (bf16) shared via LDS; O += P * V^T.
__global__ __launch_bounds__(256) void attn(
    const unsigned short* __restrict__ QT,
    const unsigned short* __restrict__ KT,
    const unsigned short* __restrict__ V,
    const float* __restrict__ x,
    const float* __restrict__ alpha_p,
    float* __restrict__ out)
{
    const int bi = blockIdx.x;
    const int b  = bi & 7;          // batch = bid%8 -> one batch per XCD (L2 locality)
    const int n0 = (bi >> 3) * 32;
    const int t = threadIdx.x;
    const int wid = t >> 6;
    const int l = t & 63;
    const int lg = l >> 4, lr = l & 15;

    __shared__ unsigned short Qlds[32][72];
    __shared__ unsigned short Klds[64][72];
    __shared__ unsigned short Plds[32][72];
    __shared__ float TMp[4][32];
    __shared__ float Spt[4][32];
    __shared__ float Fbuf[32];
    __shared__ float MNb[32];
    __shared__ float Mrun[32];
    __shared__ float Lrun[32];

    {   // stage Q tile [32][64] bf16 (one pass, 16B/thread)
        int row = t >> 3, ch = (t & 7) << 3;
        *reinterpret_cast<uint4*>(&Qlds[row][ch]) =
            *reinterpret_cast<const uint4*>(QT + ((size_t)b*NN + n0 + row)*ND + ch);
    }
    if (t < 32) { Mrun[t] = -INFINITY; Lrun[t] = 0.f; }
    __syncthreads();

    // hoist Q B-fragments (constant across all s-tiles)
    short8 qf[2][2];
    #pragma unroll
    for (int mt = 0; mt < 2; ++mt)
        #pragma unroll
        for (int k2 = 0; k2 < 2; ++k2)
            qf[mt][k2] = *reinterpret_cast<const short8*>(&Qlds[mt*16 + lr][k2*32 + lg*8]);

    f32x4 oacc[2][8];
    #pragma unroll
    for (int mt = 0; mt < 2; ++mt)
        #pragma unroll
        for (int ct = 0; ct < 8; ++ct)
            oacc[mt][ct] = f32x4{0.f, 0.f, 0.f, 0.f};

    const unsigned short* Kb = KT + (size_t)b*NN*ND;
    const unsigned short* Vb = V + (size_t)b*NC*NN + (size_t)(wid*128)*NN;

    for (int st = 0; st < 64; ++st) {
        const int s0 = st * 64;
        // stage K tile [64][64] (2 passes, 16B/thread)
        #pragma unroll
        for (int p = 0; p < 2; ++p) {
            int id = t + 256*p;
            int row = id >> 3, ch = (id & 7) << 3;
            *reinterpret_cast<uint4*>(&Klds[row][ch]) =
                *reinterpret_cast<const uint4*>(Kb + (size_t)(s0 + row)*ND + ch);
        }
        __syncthreads();  // B0: K staged

        // S^T MFMA: lane holds S^T[s=16*wid+4*lg+bb][m=16*mt+lr]
        f32x4 sac[2];
        sac[0] = f32x4{0.f,0.f,0.f,0.f};
        sac[1] = f32x4{0.f,0.f,0.f,0.f};
        #pragma unroll
        for (int k2 = 0; k2 < 2; ++k2) {
            short8 af = *reinterpret_cast<const short8*>(&Klds[wid*16 + lr][k2*32 + lg*8]);
            #pragma unroll
            for (int mt = 0; mt < 2; ++mt)
                sac[mt] = __builtin_amdgcn_mfma_f32_16x16x32_bf16(af, qf[mt][k2], sac[mt], 0, 0, 0);
        }
        // per-column (m) max within this wave's 16 s-rows
        #pragma unroll
        for (int mt = 0; mt < 2; ++mt) {
            float tm = fmaxf(fmaxf(sac[mt][0], sac[mt][1]), fmaxf(sac[mt][2], sac[mt][3]));
            tm = fmaxf(tm, __shfl_xor(tm, 16));
            tm = fmaxf(tm, __shfl_xor(tm, 32));
            if (lg == 0) TMp[wid][mt*16 + lr] = tm;
        }
        __syncthreads();  // B1: partial maxima visible

        #pragma unroll
        for (int mt = 0; mt < 2; ++mt) {
            int m = mt*16 + lr;
            float tmax = fmaxf(fmaxf(TMp[0][m], TMp[1][m]), fmaxf(TMp[2][m], TMp[3][m]));
            float mold = Mrun[m];
            float mnew = fmaxf(mold, tmax);
            float ps0 = exp2f((sac[mt][0] - mnew) * LOG2E);
            float ps1 = exp2f((sac[mt][1] - mnew) * LOG2E);
            float ps2 = exp2f((sac[mt][2] - mnew) * LOG2E);
            float ps3 = exp2f((sac[mt][3] - mnew) * LOG2E);
            float sum = (ps0 + ps1) + (ps2 + ps3);
            sum += __shfl_xor(sum, 16);
            sum += __shfl_xor(sum, 32);
            if (lg == 0) Spt[wid][m] = sum;
            // P[m][s_local = 16*wid + 4*lg + bb], packed 4x bf16
            uint2 pk;
            pk.x = (uint32_t)f2bf(ps0) | ((uint32_t)f2bf(ps1) << 16);
            pk.y = (uint32_t)f2bf(ps2) | ((uint32_t)f2bf(ps3) << 16);
            *reinterpret_cast<uint2*>(&Plds[m][wid*16 + lg*4]) = pk;
            if (t < 16) { Fbuf[m] = exp2f((mold - mnew) * LOG2E); MNb[m] = mnew; }
        }
        __syncthreads();  // B2: P, F, partial sums visible

        if (t < 16) {     // wave0 maintains running stats
            #pragma unroll
            for (int mt = 0; mt < 2; ++mt) {
                int m = mt*16 + t;
                Lrun[m] = Lrun[m] * Fbuf[m] + ((Spt[0][m] + Spt[1][m]) + (Spt[2][m] + Spt[3][m]));
                Mrun[m] = MNb[m];
            }
        }
        // rescale O by exp(mold-mnew) for this lane's rows m = 16*mt + 4*lg + bb
        float fr[2][4];
        #pragma unroll
        for (int mt = 0; mt < 2; ++mt)
            #pragma unroll
            for (int bb = 0; bb < 4; ++bb)
                fr[mt][bb] = Fbuf[mt*16 + lg*4 + bb];
        #pragma unroll
        for (int mt = 0; mt < 2; ++mt)
            #pragma unroll
            for (int ct = 0; ct < 8; ++ct)
                #pragma unroll
                for (int bb = 0; bb < 4; ++bb)
                    oacc[mt][ct][bb] *= fr[mt][bb];

        // PV: O[m][c] += P[m][s] * V[c][s]  (V^T is B operand, read from global/L2)
        short8 pf[2][2];
        #pragma unroll
        for (int mt = 0; mt < 2; ++mt)
            #pragma unroll
            for (int k2 = 0; k2 < 2; ++k2)
                pf[mt][k2] = *reinterpret_cast<const short8*>(&Plds[mt*16 + lr][k2*32 + lg*8]);
        #pragma unroll
        for (int ct = 0; ct < 8; ++ct) {
            const unsigned short* vrow = Vb + (size_t)(ct*16 + lr)*NN + s0 + lg*8;
            short8 vf0 = *reinterpret_cast<const short8*>(vrow);
            short8 vf1 = *reinterpret_cast<const short8*>(vrow + 32);
            #pragma unroll
            for (int mt = 0; mt < 2; ++mt) {
                oacc[mt][ct] = __builtin_amdgcn_mfma_f32_16x16x32_bf16(pf[mt][0], vf0, oacc[mt][ct], 0, 0, 0);
                oacc[mt][ct] = __builtin_amdgcn_mfma_f32_16x16x32_bf16(pf[mt][1], vf1, oacc[mt][ct], 0, 0, 0);
            }
        }
        // no barrier needed here: next-iter LDS writes are fenced by B0/B1
    }
    __syncthreads();  // final Lrun update visible

    const float alpha = alpha_p[0];
    float rl[2][4];
    #pragma unroll
    for (int mt = 0; mt < 2; ++mt)
        #pragma unroll
        for (int bb = 0; bb < 4; ++bb)
            rl[mt][bb] = 1.f / Lrun[mt*16 + lg*4 + bb];

    #pragma unroll
    for (int mt = 0; mt < 2; ++mt)
        #pragma unroll
        for (int ct = 0; ct < 8; ++ct) {
            int c = wid*128 + ct*16 + lr;
            #pragma unroll
            for (int bb = 0; bb < 4; ++bb) {
                int n = n0 + mt*16 + lg*4 + bb;
                size_t idx = ((size_t)b*NC + c)*NN + n;
                out[idx] = alpha * oacc[mt][ct][bb] * rl[mt][bb] + x[idx];
            }
        }
}

extern "C" void kernel_launch(void* const* d_in, const int* in_sizes, int n_in,
                              void* d_out, int out_size, void* d_ws, size_t ws_size,
                              hipStream_t stream) {
    const float* x     = (const float*)d_in[0];
    const float* wq    = (const float*)d_in[1];
    const float* bq    = (const float*)d_in[2];
    const float* wk    = (const float*)d_in[3];
    const float* bk    = (const float*)d_in[4];
    const float* wv    = (const float*)d_in[5];
    const float* bv    = (const float*)d_in[6];
    const float* alpha = (const float*)d_in[7];

    // workspace layout (bf16): QT 4MB | KT 4MB | V 32MB  (total 41,943,040 B)
    unsigned short* QT = (unsigned short*)d_ws;
    unsigned short* KT = QT + (size_t)NB*NN*ND;
    unsigned short* V  = KT + (size_t)NB*NN*ND;

    dim3 gA(64, 5, 8);
    qkv_proj<<<gA, 256, 0, stream>>>(x, wq, bq, wk, bk, wv, bv, QT, KT, V);
    attn<<<NB * (NN/32), 256, 0, stream>>>(QT, KT, V, x, alpha, (float*)d_out);
}

// Round 2
// 514.273 us; speedup vs baseline: 1.3928x; 1.3928x over previous
//
#include <hip/hip_runtime.h>
#include <hip/hip_bf16.h>
#include <stdint.h>

#define NB 8
#define NC 512
#define NN 4096
#define ND 64

typedef __attribute__((ext_vector_type(8))) short short8;
typedef __attribute__((ext_vector_type(4))) float f32x4;

#define LOG2E 1.44269504088896340736f

static __device__ __forceinline__ unsigned short f2bf(float f) {
    union { float f; uint32_t u; } v; v.f = f;
    return (unsigned short)((v.u + 0x7fffu + ((v.u >> 16) & 1u)) >> 16);
}

// ---------------- Kernel A: fused QKV projection (per-batch GEMM) ----------
// o in [0,64): q  -> QT[b][n][o]      (bf16, [B][N][64])
// o in [64,128): k -> KT[b][n][o-64]  (bf16, [B][N][64])
// o in [128,640): v -> V[b][o-128][n] (bf16, [B][512][N])
__global__ __launch_bounds__(256) void qkv_proj(
    const float* __restrict__ x,
    const float* __restrict__ wq, const float* __restrict__ bq,
    const float* __restrict__ wk, const float* __restrict__ bk,
    const float* __restrict__ wv, const float* __restrict__ bv,
    unsigned short* __restrict__ QT, unsigned short* __restrict__ KT,
    unsigned short* __restrict__ V)
{
    const int nblk = blockIdx.x;   // 64 n-tiles of 64
    const int mblk = blockIdx.y;   // 5 m-tiles of 128
    const int b    = blockIdx.z;   // 8 batches
    const int t = threadIdx.x;
    const int wid = t >> 6;
    const int l = t & 63;
    const int lg = l >> 4, lr = l & 15;

    const int o0 = mblk * 128;
    const int n0 = nblk * 64;
    const float* xb = x + (size_t)b * NC * NN;

    __shared__ unsigned short Wlds[128][72];
    __shared__ unsigned short XT[64][72];   // X tile stored transposed [n][c]

    f32x4 acc[2][4];
    #pragma unroll
    for (int mt = 0; mt < 2; ++mt) {
        #pragma unroll
        for (int bb = 0; bb < 4; ++bb) {
            int o = o0 + wid*32 + mt*16 + lg*4 + bb;
            float bias = (o < 64) ? bq[o] : (o < 128) ? bk[o-64] : bv[o-128];
            #pragma unroll
            for (int nt = 0; nt < 4; ++nt) acc[mt][nt][bb] = bias;
        }
    }

    for (int ks = 0; ks < 8; ++ks) {
        const int c0 = ks * 64;
        __syncthreads();
        #pragma unroll
        for (int p = 0; p < 8; ++p) {
            int id = t + 256*p;
            int ol = id >> 4;
            int c4 = (id & 15) << 2;
            int o  = o0 + ol;
            const float* wr = (o < 64) ? (wq + (size_t)o*NC)
                           : (o < 128) ? (wk + (size_t)(o-64)*NC)
                                       : (wv + (size_t)(o-128)*NC);
            float4 w4 = *reinterpret_cast<const float4*>(wr + c0 + c4);
            uint2 pk;
            pk.x = (uint32_t)f2bf(w4.x) | ((uint32_t)f2bf(w4.y) << 16);
            pk.y = (uint32_t)f2bf(w4.z) | ((uint32_t)f2bf(w4.w) << 16);
            *reinterpret_cast<uint2*>(&Wlds[ol][c4]) = pk;
        }
        #pragma unroll
        for (int p = 0; p < 4; ++p) {
            int id = t + 256*p;
            int cl = id >> 4;
            int n4 = (id & 15) << 2;
            float4 x4 = *reinterpret_cast<const float4*>(xb + (size_t)(c0 + cl)*NN + n0 + n4);
            XT[n4+0][cl] = f2bf(x4.x);
            XT[n4+1][cl] = f2bf(x4.y);
            XT[n4+2][cl] = f2bf(x4.z);
            XT[n4+3][cl] = f2bf(x4.w);
        }
        __syncthreads();
        #pragma unroll
        for (int k2 = 0; k2 < 2; ++k2) {
            short8 af[2], bf[4];
            #pragma unroll
            for (int mt = 0; mt < 2; ++mt)
                af[mt] = *reinterpret_cast<const short8*>(&Wlds[wid*32 + mt*16 + lr][k2*32 + lg*8]);
            #pragma unroll
            for (int nt = 0; nt < 4; ++nt)
                bf[nt] = *reinterpret_cast<const short8*>(&XT[nt*16 + lr][k2*32 + lg*8]);
            #pragma unroll
            for (int mt = 0; mt < 2; ++mt)
                #pragma unroll
                for (int nt = 0; nt < 4; ++nt)
                    acc[mt][nt] = __builtin_amdgcn_mfma_f32_16x16x32_bf16(af[mt], bf[nt], acc[mt][nt], 0, 0, 0);
        }
    }

    #pragma unroll
    for (int mt = 0; mt < 2; ++mt) {
        #pragma unroll
        for (int nt = 0; nt < 4; ++nt) {
            int n = n0 + nt*16 + lr;
            #pragma unroll
            for (int bb = 0; bb < 4; ++bb) {
                int o = o0 + wid*32 + mt*16 + lg*4 + bb;
                unsigned short hb = f2bf(acc[mt][nt][bb]);
                if (o < 64)       QT[((size_t)b*NN + n)*ND + o] = hb;
                else if (o < 128) KT[((size_t)b*NN + n)*ND + (o-64)] = hb;
                else              V[((size_t)b*NC + (o-128))*NN + n] = hb;
            }
        }
    }
}

// ---------------- Kernel B: fused flash attention + residual ----------------
// M=64 queries/block, 8 waves. Wave w: S^T rows [16w,16w+16), PV c-slice
// [64w,64w+64). K,V,Q read direct from global (L2). Softmax stats replicated
// in registers; P shared via XOR-swizzled LDS. 2 barriers per 128-key tile.
__global__ __launch_bounds__(512) void attn(
    const unsigned short* __restrict__ QT,
    const unsigned short* __restrict__ KT,
    const unsigned short* __restrict__ V,
    const float* __restrict__ x,
    const float* __restrict__ alpha_p,
    float* __restrict__ out)
{
    const int bi = blockIdx.x;
    const int b  = bi & 7;            // batch per XCD (L2 locality)
    const int n0 = (bi >> 3) * 64;
    const int t = threadIdx.x;
    const int wid = t >> 6;           // 0..7
    const int l = t & 63;
    const int lg = l >> 4, lr = l & 15;

    __shared__ __align__(16) unsigned short Plds[64 * 128];  // [m][s^((m&7)<<3)]
    __shared__ float TMp[8][64];
    __shared__ float SPt[8][64];
    __shared__ float Fb[64];
    __shared__ float Ll[64];

    const unsigned short* Qb = QT + ((size_t)b * NN + n0) * ND;
    const unsigned short* Kb = KT + (size_t)b * NN * ND;
    const unsigned short* Vb = V + ((size_t)b * NC + 64 * wid) * NN;

    // hoist Q B-fragments: Q[m=16mt+lr][d=k2*32+lg*8]
    short8 qf[4][2];
    #pragma unroll
    for (int mt = 0; mt < 4; ++mt)
        #pragma unroll
        for (int k2 = 0; k2 < 2; ++k2)
            qf[mt][k2] = *reinterpret_cast<const short8*>(
                Qb + (size_t)(mt*16 + lr) * ND + k2*32 + lg*8);

    f32x4 oacc[4][4];   // [mt][ct]: rows m=16mt+4lg+bb, cols c=64wid+16ct+lr
    #pragma unroll
    for (int mt = 0; mt < 4; ++mt)
        #pragma unroll
        for (int ct = 0; ct < 4; ++ct)
            oacc[mt][ct] = f32x4{0.f, 0.f, 0.f, 0.f};

    float mrun[4], lrun[4];
    #pragma unroll
    for (int mt = 0; mt < 4; ++mt) { mrun[mt] = -INFINITY; lrun[mt] = 0.f; }

    const int swz = (lr & 7) << 3;

    for (int st = 0; st < 32; ++st) {
        const int s0 = st * 128;

        // ---- S^T = K·Q^T : lane holds S^T[s=s0+16wid+4lg+bb][m=16mt+lr] ----
        f32x4 sac[4];
        #pragma unroll
        for (int mt = 0; mt < 4; ++mt) sac[mt] = f32x4{0.f,0.f,0.f,0.f};
        #pragma unroll
        for (int k2 = 0; k2 < 2; ++k2) {
            short8 kf = *reinterpret_cast<const short8*>(
                Kb + (size_t)(s0 + 16*wid + lr) * ND + k2*32 + lg*8);
            #pragma unroll
            for (int mt = 0; mt < 4; ++mt)
                sac[mt] = __builtin_amdgcn_mfma_f32_16x16x32_bf16(kf, qf[mt][k2], sac[mt], 0, 0, 0);
        }
        // wave-partial column max over this wave's 16 s-rows
        #pragma unroll
        for (int mt = 0; mt < 4; ++mt) {
            float tm = fmaxf(fmaxf(sac[mt][0], sac[mt][1]), fmaxf(sac[mt][2], sac[mt][3]));
            tm = fmaxf(tm, __shfl_xor(tm, 16));
            tm = fmaxf(tm, __shfl_xor(tm, 32));
            if (lg == 0) TMp[wid][mt*16 + lr] = tm;
        }
        __syncthreads();  // B1: partial maxima visible

        // ---- softmax: stats replicated in registers ----
        float fsc[4];
        #pragma unroll
        for (int mt = 0; mt < 4; ++mt) {
            const int m = mt*16 + lr;
            float tmax = TMp[0][m];
            #pragma unroll
            for (int w = 1; w < 8; ++w) tmax = fmaxf(tmax, TMp[w][m]);
            float mnew = fmaxf(mrun[mt], tmax);
            fsc[mt] = __builtin_amdgcn_exp2f((mrun[mt] - mnew) * LOG2E);
            float p0 = __builtin_amdgcn_exp2f((sac[mt][0] - mnew) * LOG2E);
            float p1 = __builtin_amdgcn_exp2f((sac[mt][1] - mnew) * LOG2E);
            float p2 = __builtin_amdgcn_exp2f((sac[mt][2] - mnew) * LOG2E);
            float p3 = __builtin_amdgcn_exp2f((sac[mt][3] - mnew) * LOG2E);
            float sum = (p0 + p1) + (p2 + p3);
            sum += __shfl_xor(sum, 16);
            sum += __shfl_xor(sum, 32);
            if (lg == 0) SPt[wid][m] = sum;
            if (wid == 0 && lg == 0) Fb[m] = fsc[mt];
            uint2 pk;
            pk.x = (uint32_t)f2bf(p0) | ((uint32_t)f2bf(p1) << 16);
            pk.y = (uint32_t)f2bf(p2) | ((uint32_t)f2bf(p3) << 16);
            // P[m][s_local=16wid+4lg+bb], s XOR-swizzled by (m&7)<<3
            *reinterpret_cast<uint2*>(&Plds[(m << 7) + ((16*wid + 4*lg) ^ swz)]) = pk;
            mrun[mt] = mnew;
        }
        __syncthreads();  // B2: P, partial sums, Fb visible

        #pragma unroll
        for (int mt = 0; mt < 4; ++mt) {
            const int m = mt*16 + lr;
            float ts = SPt[0][m];
            #pragma unroll
            for (int w = 1; w < 8; ++w) ts += SPt[w][m];
            lrun[mt] = lrun[mt] * fsc[mt] + ts;
        }

        // ---- rescale O: rows m=16mt+4lg+bb need Fb[m] ----
        #pragma unroll
        for (int mt = 0; mt < 4; ++mt) {
            float4 fr = *reinterpret_cast<const float4*>(&Fb[mt*16 + 4*lg]);
            #pragma unroll
            for (int ct = 0; ct < 4; ++ct) {
                oacc[mt][ct][0] *= fr.x;
                oacc[mt][ct][1] *= fr.y;
                oacc[mt][ct][2] *= fr.z;
                oacc[mt][ct][3] *= fr.w;
            }
        }

        // ---- PV: O[m][c] += P[m][s] * V[c][s], V^T direct from global/L2 ----
        #pragma unroll 2
        for (int k2 = 0; k2 < 4; ++k2) {
            short8 pf[4], vf[4];
            #pragma unroll
            for (int mt = 0; mt < 4; ++mt) {
                const int m = mt*16 + lr;
                pf[mt] = *reinterpret_cast<const short8*>(
                    &Plds[(m << 7) + ((k2*32 + lg*8) ^ swz)]);
            }
            #pragma unroll
            for (int ct = 0; ct < 4; ++ct)
                vf[ct] = *reinterpret_cast<const short8*>(
                    Vb + (size_t)(ct*16 + lr) * NN + s0 + k2*32 + lg*8);
            #pragma unroll
            for (int mt = 0; mt < 4; ++mt)
                #pragma unroll
                for (int ct = 0; ct < 4; ++ct)
                    oacc[mt][ct] = __builtin_amdgcn_mfma_f32_16x16x32_bf16(pf[mt], vf[ct], oacc[mt][ct], 0, 0, 0);
        }
        // no barrier: next-tile LDS writes all occur after next B1
    }

    if (wid == 0 && lg == 0) {
        #pragma unroll
        for (int mt = 0; mt < 4; ++mt) Ll[mt*16 + lr] = lrun[mt];
    }
    __syncthreads();

    const float alpha = alpha_p[0];
    #pragma unroll
    for (int mt = 0; mt < 4; ++mt) {
        float4 l4 = *reinterpret_cast<const float4*>(&Ll[mt*16 + 4*lg]);
        float ar0 = alpha / l4.x, ar1 = alpha / l4.y, ar2 = alpha / l4.z, ar3 = alpha / l4.w;
        #pragma unroll
        for (int ct = 0; ct < 4; ++ct) {
            const int c = 64*wid + 16*ct + lr;
            const size_t base = ((size_t)b*NC + c)*NN + n0 + mt*16 + 4*lg;
            float4 x4 = *reinterpret_cast<const float4*>(x + base);
            float4 o4;
            o4.x = oacc[mt][ct][0] * ar0 + x4.x;
            o4.y = oacc[mt][ct][1] * ar1 + x4.y;
            o4.z = oacc[mt][ct][2] * ar2 + x4.z;
            o4.w = oacc[mt][ct][3] * ar3 + x4.w;
            *reinterpret_cast<float4*>(out + base) = o4;
        }
    }
}

extern "C" void kernel_launch(void* const* d_in, const int* in_sizes, int n_in,
                              void* d_out, int out_size, void* d_ws, size_t ws_size,
                              hipStream_t stream) {
    const float* x     = (const float*)d_in[0];
    const float* wq    = (const float*)d_in[1];
    const float* bq    = (const float*)d_in[2];
    const float* wk    = (const float*)d_in[3];
    const float* bk    = (const float*)d_in[4];
    const float* wv    = (const float*)d_in[5];
    const float* bv    = (const float*)d_in[6];
    const float* alpha = (const float*)d_in[7];

    unsigned short* QT = (unsigned short*)d_ws;
    unsigned short* KT = QT + (size_t)NB*NN*ND;
    unsigned short* V  = KT + (size_t)NB*NN*ND;

    dim3 gA(64, 5, 8);
    qkv_proj<<<gA, 256, 0, stream>>>(x, wq, bq, wk, bk, wv, bv, QT, KT, V);
    attn<<<NB * (NN/64), 512, 0, stream>>>(QT, KT, V, x, alpha, (float*)d_out);
}

// Round 3
// 364.470 us; speedup vs baseline: 1.9652x; 1.4110x over previous
//
#include <hip/hip_runtime.h>
#include <hip/hip_bf16.h>
#include <stdint.h>

#define NB 8
#define NC 512
#define NN 4096
#define ND 64

typedef __attribute__((ext_vector_type(8))) short short8;
typedef __attribute__((ext_vector_type(4))) float f32x4;

#define LOG2E 1.44269504088896340736f

static __device__ __forceinline__ unsigned short f2bf(float f) {
    union { float f; uint32_t u; } v; v.f = f;
    return (unsigned short)((v.u + 0x7fffu + ((v.u >> 16) & 1u)) >> 16);
}

// ---------------- Kernel A: fused QKV projection (per-batch GEMM) ----------
// o in [0,64): q  -> QT[b][n][o]      (bf16)
// o in [64,128): k -> KT[b][n][o-64]  (bf16)
// o in [128,640): v -> V[b][o-128][n] (fp8 e4m3)
__global__ __launch_bounds__(256) void qkv_proj(
    const float* __restrict__ x,
    const float* __restrict__ wq, const float* __restrict__ bq,
    const float* __restrict__ wk, const float* __restrict__ bk,
    const float* __restrict__ wv, const float* __restrict__ bv,
    unsigned short* __restrict__ QT, unsigned short* __restrict__ KT,
    unsigned char* __restrict__ V)
{
    const int nblk = blockIdx.x;
    const int mblk = blockIdx.y;
    const int b    = blockIdx.z;
    const int t = threadIdx.x;
    const int wid = t >> 6;
    const int l = t & 63;
    const int lg = l >> 4, lr = l & 15;

    const int o0 = mblk * 128;
    const int n0 = nblk * 64;
    const float* xb = x + (size_t)b * NC * NN;

    __shared__ unsigned short Wlds[128][72];
    __shared__ unsigned short XT[64][72];

    f32x4 acc[2][4];
    #pragma unroll
    for (int mt = 0; mt < 2; ++mt) {
        #pragma unroll
        for (int bb = 0; bb < 4; ++bb) {
            int o = o0 + wid*32 + mt*16 + lg*4 + bb;
            float bias = (o < 64) ? bq[o] : (o < 128) ? bk[o-64] : bv[o-128];
            #pragma unroll
            for (int nt = 0; nt < 4; ++nt) acc[mt][nt][bb] = bias;
        }
    }

    for (int ks = 0; ks < 8; ++ks) {
        const int c0 = ks * 64;
        __syncthreads();
        #pragma unroll
        for (int p = 0; p < 8; ++p) {
            int id = t + 256*p;
            int ol = id >> 4;
            int c4 = (id & 15) << 2;
            int o  = o0 + ol;
            const float* wr = (o < 64) ? (wq + (size_t)o*NC)
                           : (o < 128) ? (wk + (size_t)(o-64)*NC)
                                       : (wv + (size_t)(o-128)*NC);
            float4 w4 = *reinterpret_cast<const float4*>(wr + c0 + c4);
            uint2 pk;
            pk.x = (uint32_t)f2bf(w4.x) | ((uint32_t)f2bf(w4.y) << 16);
            pk.y = (uint32_t)f2bf(w4.z) | ((uint32_t)f2bf(w4.w) << 16);
            *reinterpret_cast<uint2*>(&Wlds[ol][c4]) = pk;
        }
        #pragma unroll
        for (int p = 0; p < 4; ++p) {
            int id = t + 256*p;
            int cl = id >> 4;
            int n4 = (id & 15) << 2;
            float4 x4 = *reinterpret_cast<const float4*>(xb + (size_t)(c0 + cl)*NN + n0 + n4);
            XT[n4+0][cl] = f2bf(x4.x);
            XT[n4+1][cl] = f2bf(x4.y);
            XT[n4+2][cl] = f2bf(x4.z);
            XT[n4+3][cl] = f2bf(x4.w);
        }
        __syncthreads();
        #pragma unroll
        for (int k2 = 0; k2 < 2; ++k2) {
            short8 af[2], bf[4];
            #pragma unroll
            for (int mt = 0; mt < 2; ++mt)
                af[mt] = *reinterpret_cast<const short8*>(&Wlds[wid*32 + mt*16 + lr][k2*32 + lg*8]);
            #pragma unroll
            for (int nt = 0; nt < 4; ++nt)
                bf[nt] = *reinterpret_cast<const short8*>(&XT[nt*16 + lr][k2*32 + lg*8]);
            #pragma unroll
            for (int mt = 0; mt < 2; ++mt)
                #pragma unroll
                for (int nt = 0; nt < 4; ++nt)
                    acc[mt][nt] = __builtin_amdgcn_mfma_f32_16x16x32_bf16(af[mt], bf[nt], acc[mt][nt], 0, 0, 0);
        }
    }

    #pragma unroll
    for (int mt = 0; mt < 2; ++mt) {
        #pragma unroll
        for (int nt = 0; nt < 4; ++nt) {
            int n = n0 + nt*16 + lr;
            #pragma unroll
            for (int bb = 0; bb < 4; ++bb) {
                int o = o0 + wid*32 + mt*16 + lg*4 + bb;
                float av = acc[mt][nt][bb];
                if (o < 64)       QT[((size_t)b*NN + n)*ND + o] = f2bf(av);
                else if (o < 128) KT[((size_t)b*NN + n)*ND + (o-64)] = f2bf(av);
                else {
                    int pk8 = __builtin_amdgcn_cvt_pk_fp8_f32(av, 0.f, 0, false);
                    V[((size_t)b*NC + (o-128))*NN + n] = (unsigned char)(pk8 & 0xff);
                }
            }
        }
    }
}

// ---------------- Kernel B: fused flash attention + residual ----------------
// M=128 queries/block, 8 waves, KVBLK=128. Wave w: S^T rows [16w,16w+16),
// PV c-slice [64w,64w+64). QK^T bf16; P,V fp8 e4m3. V L2-resident (2MB/batch).
__global__ __launch_bounds__(512, 2) void attn(
    const unsigned short* __restrict__ QT,
    const unsigned short* __restrict__ KT,
    const unsigned char* __restrict__ V,
    const float* __restrict__ x,
    const float* __restrict__ alpha_p,
    float* __restrict__ out)
{
    const int bi = blockIdx.x;
    const int b  = bi & 7;            // batch per XCD
    const int n0 = (bi >> 3) * 128;
    const int t = threadIdx.x;
    const int wid = t >> 6;
    const int l = t & 63;
    const int lg = l >> 4, lr = l & 15;

    __shared__ __align__(16) unsigned short Qlds[128*64];   // [m][d^(8*(m&7))]
    __shared__ __align__(16) unsigned char  Plds[128*128];  // [m][s^(8*(m&15))]
    __shared__ float TMp[128][12];
    __shared__ float SPt[128][12];
    __shared__ float Fb[128];
    __shared__ float Ll[128];

    const unsigned short* Qb = QT + ((size_t)b*NN + n0)*ND;
    const unsigned short* Kb = KT + (size_t)b*NN*ND;
    const unsigned char*  Vb = V + ((size_t)b*NC + 64*wid)*NN;

    // stage Q tile [128][64] bf16, XOR-swizzled
    #pragma unroll
    for (int i = 0; i < 2; ++i) {
        int idx = t + 512*i;
        int m = idx >> 3, c8 = idx & 7;
        short8 v = *reinterpret_cast<const short8*>(Qb + m*ND + c8*8);
        *reinterpret_cast<short8*>(&Qlds[m*64 + ((c8*8) ^ (8*(m&7)))]) = v;
    }
    __syncthreads();

    f32x4 oacc[8][4];
    #pragma unroll
    for (int mt = 0; mt < 8; ++mt)
        #pragma unroll
        for (int ct = 0; ct < 4; ++ct)
            oacc[mt][ct] = f32x4{0.f, 0.f, 0.f, 0.f};

    float mrun[8], lrun[8];
    #pragma unroll
    for (int mt = 0; mt < 8; ++mt) { mrun[mt] = -INFINITY; lrun[mt] = 0.f; }

    const int qswz = 8*(lr & 7);
    const int pswz = 8*lr;

    // preload K frags for tile 0; prefetch V k2=0 of tile 0
    short8 kf0 = *reinterpret_cast<const short8*>(Kb + (size_t)(16*wid + lr)*ND + lg*8);
    short8 kf1 = *reinterpret_cast<const short8*>(Kb + (size_t)(16*wid + lr)*ND + 32 + lg*8);
    long vf[4];
    #pragma unroll
    for (int ct = 0; ct < 4; ++ct)
        vf[ct] = *reinterpret_cast<const long*>(Vb + (size_t)(ct*16 + lr)*NN + lg*8);

    for (int st = 0; st < 32; ++st) {
        const int s0 = st * 128;
        const int s0n = (st < 31) ? s0 + 128 : s0;

        // ---- QK^T (bf16): lane holds S^T[s=s0+16wid+4lg+bb][m=16mt+lr] ----
        f32x4 sac[8];
        #pragma unroll
        for (int mt = 0; mt < 8; ++mt) {
            short8 qa = *reinterpret_cast<const short8*>(
                &Qlds[(16*mt + lr)*64 + ((lg*8) ^ qswz)]);
            sac[mt] = __builtin_amdgcn_mfma_f32_16x16x32_bf16(kf0, qa, f32x4{0.f,0.f,0.f,0.f}, 0, 0, 0);
        }
        #pragma unroll
        for (int mt = 0; mt < 8; ++mt) {
            short8 qb = *reinterpret_cast<const short8*>(
                &Qlds[(16*mt + lr)*64 + ((32 + lg*8) ^ qswz)]);
            sac[mt] = __builtin_amdgcn_mfma_f32_16x16x32_bf16(kf1, qb, sac[mt], 0, 0, 0);
        }

        // ---- wave-partial column max; prefetch next K ----
        #pragma unroll
        for (int mt = 0; mt < 8; ++mt) {
            float tm = fmaxf(fmaxf(sac[mt][0], sac[mt][1]), fmaxf(sac[mt][2], sac[mt][3]));
            tm = fmaxf(tm, __shfl_xor(tm, 16));
            tm = fmaxf(tm, __shfl_xor(tm, 32));
            if (lg == 0) TMp[16*mt + lr][wid] = tm;
        }
        kf0 = *reinterpret_cast<const short8*>(Kb + (size_t)(s0n + 16*wid + lr)*ND + lg*8);
        kf1 = *reinterpret_cast<const short8*>(Kb + (size_t)(s0n + 16*wid + lr)*ND + 32 + lg*8);
        __syncthreads();  // B1

        // ---- softmax (stats replicated in regs; cross-wave via TMp) ----
        float fsc[8];
        #pragma unroll
        for (int mt = 0; mt < 8; ++mt) {
            const int m = 16*mt + lr;
            float4 ta = *reinterpret_cast<const float4*>(&TMp[m][0]);
            float4 tb = *reinterpret_cast<const float4*>(&TMp[m][4]);
            float tmax = fmaxf(fmaxf(fmaxf(ta.x, ta.y), fmaxf(ta.z, ta.w)),
                               fmaxf(fmaxf(tb.x, tb.y), fmaxf(tb.z, tb.w)));
            float mnew = fmaxf(mrun[mt], tmax);
            fsc[mt] = __builtin_amdgcn_exp2f((mrun[mt] - mnew) * LOG2E);
            mrun[mt] = mnew;
            if (wid == 0 && lg == 0) Fb[m] = fsc[mt];
            float p0 = __builtin_amdgcn_exp2f((sac[mt][0] - mnew) * LOG2E);
            float p1 = __builtin_amdgcn_exp2f((sac[mt][1] - mnew) * LOG2E);
            float p2 = __builtin_amdgcn_exp2f((sac[mt][2] - mnew) * LOG2E);
            float p3 = __builtin_amdgcn_exp2f((sac[mt][3] - mnew) * LOG2E);
            float sum = (p0 + p1) + (p2 + p3);
            sum += __shfl_xor(sum, 16);
            sum += __shfl_xor(sum, 32);
            if (lg == 0) SPt[m][wid] = sum;
            int d = __builtin_amdgcn_cvt_pk_fp8_f32(p0, p1, 0, false);
            d = __builtin_amdgcn_cvt_pk_fp8_f32(p2, p3, d, true);
            *reinterpret_cast<int*>(&Plds[m*128 + ((16*wid + 4*lg) ^ pswz)]) = d;
        }
        __syncthreads();  // B2

        // wave0 maintains l (others don't need it until epilogue)
        if (wid == 0) {
            #pragma unroll
            for (int mt = 0; mt < 8; ++mt) {
                const int m = 16*mt + lr;
                float4 sa = *reinterpret_cast<const float4*>(&SPt[m][0]);
                float4 sb = *reinterpret_cast<const float4*>(&SPt[m][4]);
                float ts = ((sa.x + sa.y) + (sa.z + sa.w)) + ((sb.x + sb.y) + (sb.z + sb.w));
                lrun[mt] = lrun[mt] * fsc[mt] + ts;
            }
        }

        // ---- rescale O ----
        #pragma unroll
        for (int mt = 0; mt < 8; ++mt) {
            float4 fr = *reinterpret_cast<const float4*>(&Fb[16*mt + 4*lg]);
            #pragma unroll
            for (int ct = 0; ct < 4; ++ct) {
                oacc[mt][ct][0] *= fr.x;
                oacc[mt][ct][1] *= fr.y;
                oacc[mt][ct][2] *= fr.z;
                oacc[mt][ct][3] *= fr.w;
            }
        }

        // ---- PV (fp8): O[m][c] += P[m][s] * V[c][s] ----
        #pragma unroll
        for (int k2 = 0; k2 < 4; ++k2) {
            const int snext = (k2 < 3) ? (s0 + (k2+1)*32) : s0n;
            long vfn[4];
            #pragma unroll
            for (int ct = 0; ct < 4; ++ct)
                vfn[ct] = *reinterpret_cast<const long*>(
                    Vb + (size_t)(ct*16 + lr)*NN + snext + lg*8);
            #pragma unroll
            for (int mt = 0; mt < 8; ++mt) {
                const int m = 16*mt + lr;
                long pf = *reinterpret_cast<const long*>(
                    &Plds[m*128 + ((k2*32 + 8*lg) ^ pswz)]);
                #pragma unroll
                for (int ct = 0; ct < 4; ++ct)
                    oacc[mt][ct] = __builtin_amdgcn_mfma_f32_16x16x32_fp8_fp8(
                        pf, vf[ct], oacc[mt][ct], 0, 0, 0);
            }
            #pragma unroll
            for (int ct = 0; ct < 4; ++ct) vf[ct] = vfn[ct];
        }
    }

    if (wid == 0 && lg == 0) {
        #pragma unroll
        for (int mt = 0; mt < 8; ++mt) Ll[16*mt + lr] = lrun[mt];
    }
    __syncthreads();

    const float alpha = alpha_p[0];
    #pragma unroll
    for (int mt = 0; mt < 8; ++mt) {
        float4 l4 = *reinterpret_cast<const float4*>(&Ll[16*mt + 4*lg]);
        float ar0 = alpha / l4.x, ar1 = alpha / l4.y, ar2 = alpha / l4.z, ar3 = alpha / l4.w;
        #pragma unroll
        for (int ct = 0; ct < 4; ++ct) {
            const int c = 64*wid + 16*ct + lr;
            const size_t base = ((size_t)b*NC + c)*NN + n0 + 16*mt + 4*lg;
            float4 x4 = *reinterpret_cast<const float4*>(x + base);
            float4 o4;
            o4.x = oacc[mt][ct][0] * ar0 + x4.x;
            o4.y = oacc[mt][ct][1] * ar1 + x4.y;
            o4.z = oacc[mt][ct][2] * ar2 + x4.z;
            o4.w = oacc[mt][ct][3] * ar3 + x4.w;
            *reinterpret_cast<float4*>(out + base) = o4;
        }
    }
}

extern "C" void kernel_launch(void* const* d_in, const int* in_sizes, int n_in,
                              void* d_out, int out_size, void* d_ws, size_t ws_size,
                              hipStream_t stream) {
    const float* x     = (const float*)d_in[0];
    const float* wq    = (const float*)d_in[1];
    const float* bq    = (const float*)d_in[2];
    const float* wk    = (const float*)d_in[3];
    const float* bk    = (const float*)d_in[4];
    const float* wv    = (const float*)d_in[5];
    const float* bv    = (const float*)d_in[6];
    const float* alpha = (const float*)d_in[7];

    // ws: QT bf16 4MB | KT bf16 4MB | V fp8 16MB
    unsigned short* QT = (unsigned short*)d_ws;
    unsigned short* KT = QT + (size_t)NB*NN*ND;
    unsigned char*  V  = (unsigned char*)(KT + (size_t)NB*NN*ND);

    dim3 gA(64, 5, 8);
    qkv_proj<<<gA, 256, 0, stream>>>(x, wq, bq, wk, bk, wv, bv, QT, KT, V);
    attn<<<NB * (NN/128), 512, 0, stream>>>(QT, KT, V, x, alpha, (float*)d_out);
}

// Round 4
// 283.099 us; speedup vs baseline: 2.5301x; 1.2874x over previous
//
#include <hip/hip_runtime.h>
#include <hip/hip_bf16.h>
#include <stdint.h>

#define NB 8
#define NC 512
#define NN 4096
#define ND 64

typedef __attribute__((ext_vector_type(8))) short short8;
typedef __attribute__((ext_vector_type(4))) float f32x4;

#define LOG2E 1.44269504088896340736f

static __device__ __forceinline__ unsigned short f2bf(float f) {
    union { float f; uint32_t u; } v; v.f = f;
    return (unsigned short)((v.u + 0x7fffu + ((v.u >> 16) & 1u)) >> 16);
}

// ---------------- Kernel A: fused QKV projection (per-batch GEMM) ----------
// o in [0,64): q  -> QT[b][n][o]      (bf16)
// o in [64,128): k -> KT[b][n][o-64]  (bf16)
// o in [128,640): v -> V[b][o-128][n] (fp8 e4m3)
__global__ __launch_bounds__(256) void qkv_proj(
    const float* __restrict__ x,
    const float* __restrict__ wq, const float* __restrict__ bq,
    const float* __restrict__ wk, const float* __restrict__ bk,
    const float* __restrict__ wv, const float* __restrict__ bv,
    unsigned short* __restrict__ QT, unsigned short* __restrict__ KT,
    unsigned char* __restrict__ V)
{
    const int nblk = blockIdx.x;
    const int mblk = blockIdx.y;
    const int b    = blockIdx.z;
    const int t = threadIdx.x;
    const int wid = t >> 6;
    const int l = t & 63;
    const int lg = l >> 4, lr = l & 15;

    const int o0 = mblk * 128;
    const int n0 = nblk * 64;
    const float* xb = x + (size_t)b * NC * NN;

    __shared__ unsigned short Wlds[128][72];
    __shared__ unsigned short XT[64][72];

    f32x4 acc[2][4];
    #pragma unroll
    for (int mt = 0; mt < 2; ++mt) {
        #pragma unroll
        for (int bb = 0; bb < 4; ++bb) {
            int o = o0 + wid*32 + mt*16 + lg*4 + bb;
            float bias = (o < 64) ? bq[o] : (o < 128) ? bk[o-64] : bv[o-128];
            #pragma unroll
            for (int nt = 0; nt < 4; ++nt) acc[mt][nt][bb] = bias;
        }
    }

    for (int ks = 0; ks < 8; ++ks) {
        const int c0 = ks * 64;
        __syncthreads();
        // stage W tile [128 o][64 c] fp32 -> bf16
        #pragma unroll
        for (int p = 0; p < 8; ++p) {
            int id = t + 256*p;
            int ol = id >> 4;
            int c4 = (id & 15) << 2;
            int o  = o0 + ol;
            const float* wr = (o < 64) ? (wq + (size_t)o*NC)
                           : (o < 128) ? (wk + (size_t)(o-64)*NC)
                                       : (wv + (size_t)(o-128)*NC);
            float4 w4 = *reinterpret_cast<const float4*>(wr + c0 + c4);
            uint2 pk;
            pk.x = (uint32_t)f2bf(w4.x) | ((uint32_t)f2bf(w4.y) << 16);
            pk.y = (uint32_t)f2bf(w4.z) | ((uint32_t)f2bf(w4.w) << 16);
            *reinterpret_cast<uint2*>(&Wlds[ol][c4]) = pk;
        }
        // stage X tile [64c][64n] -> XT[n][c], 4x4 register micro-transpose
        {
            int cl = (t >> 4) << 2;          // c-quad 0..60
            int n4 = (t & 15) << 2;          // n-quad 0..60
            const float* xr = xb + (size_t)(c0 + cl)*NN + n0 + n4;
            float4 r0 = *reinterpret_cast<const float4*>(xr);
            float4 r1 = *reinterpret_cast<const float4*>(xr + NN);
            float4 r2 = *reinterpret_cast<const float4*>(xr + 2*(size_t)NN);
            float4 r3 = *reinterpret_cast<const float4*>(xr + 3*(size_t)NN);
            uint2 w;
            w.x = (uint32_t)f2bf(r0.x) | ((uint32_t)f2bf(r1.x) << 16);
            w.y = (uint32_t)f2bf(r2.x) | ((uint32_t)f2bf(r3.x) << 16);
            *reinterpret_cast<uint2*>(&XT[n4+0][cl]) = w;
            w.x = (uint32_t)f2bf(r0.y) | ((uint32_t)f2bf(r1.y) << 16);
            w.y = (uint32_t)f2bf(r2.y) | ((uint32_t)f2bf(r3.y) << 16);
            *reinterpret_cast<uint2*>(&XT[n4+1][cl]) = w;
            w.x = (uint32_t)f2bf(r0.z) | ((uint32_t)f2bf(r1.z) << 16);
            w.y = (uint32_t)f2bf(r2.z) | ((uint32_t)f2bf(r3.z) << 16);
            *reinterpret_cast<uint2*>(&XT[n4+2][cl]) = w;
            w.x = (uint32_t)f2bf(r0.w) | ((uint32_t)f2bf(r1.w) << 16);
            w.y = (uint32_t)f2bf(r2.w) | ((uint32_t)f2bf(r3.w) << 16);
            *reinterpret_cast<uint2*>(&XT[n4+3][cl]) = w;
        }
        __syncthreads();
        #pragma unroll
        for (int k2 = 0; k2 < 2; ++k2) {
            short8 af[2], bf[4];
            #pragma unroll
            for (int mt = 0; mt < 2; ++mt)
                af[mt] = *reinterpret_cast<const short8*>(&Wlds[wid*32 + mt*16 + lr][k2*32 + lg*8]);
            #pragma unroll
            for (int nt = 0; nt < 4; ++nt)
                bf[nt] = *reinterpret_cast<const short8*>(&XT[nt*16 + lr][k2*32 + lg*8]);
            #pragma unroll
            for (int mt = 0; mt < 2; ++mt)
                #pragma unroll
                for (int nt = 0; nt < 4; ++nt)
                    acc[mt][nt] = __builtin_amdgcn_mfma_f32_16x16x32_bf16(af[mt], bf[nt], acc[mt][nt], 0, 0, 0);
        }
    }

    #pragma unroll
    for (int mt = 0; mt < 2; ++mt) {
        #pragma unroll
        for (int nt = 0; nt < 4; ++nt) {
            int n = n0 + nt*16 + lr;
            #pragma unroll
            for (int bb = 0; bb < 4; ++bb) {
                int o = o0 + wid*32 + mt*16 + lg*4 + bb;
                float av = acc[mt][nt][bb];
                if (o < 64)       QT[((size_t)b*NN + n)*ND + o] = f2bf(av);
                else if (o < 128) KT[((size_t)b*NN + n)*ND + (o-64)] = f2bf(av);
                else {
                    int pk8 = __builtin_amdgcn_cvt_pk_fp8_f32(av, 0.f, 0, false);
                    V[((size_t)b*NC + (o-128))*NN + n] = (unsigned char)(pk8 & 0xff);
                }
            }
        }
    }
}

// ---------------- Kernel B: fused flash attention + residual ----------------
// M=128 q/block, 8 waves, KVBLK=128, ONE barrier per tile.
// QK^T m-split: wave w computes S^T[all 128 s][m=16w..16w+16) from swizzled
// K LDS (dbuf); softmax wave-local (in-lane trees + shfl). P fp8 -> dbuf LDS.
// PV c-split: wave w owns c-slice [64w,64w+64), V fp8 direct from global/L2.
// Defer-rescale (THR=5): O-rescale only when running max grows (rare).
__global__ __launch_bounds__(512, 2) void attn(
    const unsigned short* __restrict__ QT,
    const unsigned short* __restrict__ KT,
    const unsigned char* __restrict__ V,
    const float* __restrict__ x,
    const float* __restrict__ alpha_p,
    float* __restrict__ out)
{
    const int bi = blockIdx.x;
    const int b  = bi & 7;            // batch per XCD (L2 locality)
    const int n0 = (bi >> 3) * 128;
    const int t = threadIdx.x;
    const int wid = t >> 6;
    const int l = t & 63;
    const int lg = l >> 4, lr = l & 15;

    __shared__ __align__(16) unsigned short Klds[2][128*64];  // swizzled [s][d^(8*(s&7))]
    __shared__ __align__(16) unsigned char  Plds[2][128*128]; // [m][s^(8*(m&15))]
    __shared__ float Fb[2][128];
    __shared__ int   Flg[2][8];
    __shared__ float Ll[128];

    const unsigned short* Qb = QT + ((size_t)b*NN + n0)*ND;
    const unsigned short* Kb = KT + (size_t)b*NN*ND;
    const unsigned char*  Vb = V + ((size_t)b*NC + 64*wid)*NN;

    // Q B-frags for this wave's 16 queries (m = 16*wid + lr), hoisted for all tiles
    short8 qf0 = *reinterpret_cast<const short8*>(Qb + (size_t)(16*wid + lr)*ND + lg*8);
    short8 qf1 = *reinterpret_cast<const short8*>(Qb + (size_t)(16*wid + lr)*ND + 32 + lg*8);

    // K staging: thread copies 8-short chunks t and t+512 of the 8192-short tile
    const int kc0_row = t >> 3,          kc0_d = 8*(t & 7);
    const int kc1_row = (t + 512) >> 3,  kc1_d = 8*((t + 512) & 7);
    const int kc0_dst = kc0_row*64 + (kc0_d ^ (8*(kc0_row & 7)));
    const int kc1_dst = kc1_row*64 + (kc1_d ^ (8*(kc1_row & 7)));

    short8 kr0 = *reinterpret_cast<const short8*>(Kb + (size_t)t*8);
    short8 kr1 = *reinterpret_cast<const short8*>(Kb + 4096 + (size_t)t*8);
    *reinterpret_cast<short8*>(&Klds[0][kc0_dst]) = kr0;
    *reinterpret_cast<short8*>(&Klds[0][kc1_dst]) = kr1;

    f32x4 oacc[8][4];
    #pragma unroll
    for (int mt = 0; mt < 8; ++mt)
        #pragma unroll
        for (int ct = 0; ct < 4; ++ct)
            oacc[mt][ct] = f32x4{0.f, 0.f, 0.f, 0.f};

    float mrun = -INFINITY, lrun = 0.f;

    long vf[4];
    #pragma unroll
    for (int ct = 0; ct < 4; ++ct)
        vf[ct] = *reinterpret_cast<const long*>(Vb + (size_t)(ct*16 + lr)*NN + lg*8);

    __syncthreads();

    const int kswz = 8*(lr & 7);
    const int pswz = 8*lr;

    int cur = 0;
    for (int st = 0; st < 32; ++st) {
        const int s0 = st * 128;
        const int s0n = (st < 31) ? s0 + 128 : s0;

        // issue K(t+1) global loads early (latency hides under QK^T/softmax)
        kr0 = *reinterpret_cast<const short8*>(Kb + (size_t)s0n*ND + (size_t)t*8);
        kr1 = *reinterpret_cast<const short8*>(Kb + (size_t)s0n*ND + 4096 + (size_t)t*8);

        // ---- QK^T: wave-local, S^T[s=16st8+4lg+r][m=16wid+lr] ----
        f32x4 sac[8];
        #pragma unroll
        for (int st8 = 0; st8 < 8; ++st8) {
            const unsigned short* kp = &Klds[cur][(16*st8 + lr)*64];
            short8 a0 = *reinterpret_cast<const short8*>(kp + ((8*lg) ^ kswz));
            short8 a1 = *reinterpret_cast<const short8*>(kp + ((32 + 8*lg) ^ kswz));
            sac[st8] = __builtin_amdgcn_mfma_f32_16x16x32_bf16(a0, qf0, f32x4{0.f,0.f,0.f,0.f}, 0, 0, 0);
            sac[st8] = __builtin_amdgcn_mfma_f32_16x16x32_bf16(a1, qf1, sac[st8], 0, 0, 0);
        }

        // stage K(t+1) into other buffer (safe: all waves past barrier(t-1))
        *reinterpret_cast<short8*>(&Klds[cur^1][kc0_dst]) = kr0;
        *reinterpret_cast<short8*>(&Klds[cur^1][kc1_dst]) = kr1;

        // ---- wave-local softmax over this lane's column m = 16wid+lr ----
        float mx01 = fmaxf(fmaxf(sac[0][0], sac[0][1]), fmaxf(sac[0][2], sac[0][3]));
        #pragma unroll
        for (int st8 = 1; st8 < 8; ++st8) {
            float m2 = fmaxf(fmaxf(sac[st8][0], sac[st8][1]), fmaxf(sac[st8][2], sac[st8][3]));
            mx01 = fmaxf(mx01, m2);
        }
        float tmax = fmaxf(mx01, __shfl_xor(mx01, 16));
        tmax = fmaxf(tmax, __shfl_xor(tmax, 32));

        bool trig = tmax > mrun + 5.0f;                 // defer-rescale threshold
        unsigned long long bal = __ballot(trig);
        float mnew = bal ? fmaxf(mrun, tmax) : mrun;
        float fsc = __builtin_amdgcn_exp2f((mrun - mnew) * LOG2E);
        if (l == 0) Flg[cur][wid] = (bal != 0ULL);
        if (lg == 0) Fb[cur][16*wid + lr] = fsc;

        const float mL = mnew * LOG2E;
        const int prow = (16*wid + lr) * 128;
        float colsum = 0.f;
        #pragma unroll
        for (int st8 = 0; st8 < 8; ++st8) {
            float p0 = __builtin_amdgcn_exp2f(sac[st8][0]*LOG2E - mL);
            float p1 = __builtin_amdgcn_exp2f(sac[st8][1]*LOG2E - mL);
            float p2 = __builtin_amdgcn_exp2f(sac[st8][2]*LOG2E - mL);
            float p3 = __builtin_amdgcn_exp2f(sac[st8][3]*LOG2E - mL);
            colsum += (p0 + p1) + (p2 + p3);
            int d = __builtin_amdgcn_cvt_pk_fp8_f32(p0, p1, 0, false);
            d = __builtin_amdgcn_cvt_pk_fp8_f32(p2, p3, d, true);
            *reinterpret_cast<int*>(&Plds[cur][prow + ((16*st8 + 4*lg) ^ pswz)]) = d;
        }
        colsum += __shfl_xor(colsum, 16);
        colsum += __shfl_xor(colsum, 32);
        lrun = lrun * fsc + colsum;
        mrun = mnew;

        __syncthreads();   // THE barrier: P(t) + K(t+1) visible; Fb/Flg(t) valid

        // ---- conditional O-rescale (block-uniform; rare after first tiles) ----
        int4 f0 = *reinterpret_cast<const int4*>(&Flg[cur][0]);
        int4 f1 = *reinterpret_cast<const int4*>(&Flg[cur][4]);
        if (f0.x | f0.y | f0.z | f0.w | f1.x | f1.y | f1.z | f1.w) {
            #pragma unroll
            for (int mt = 0; mt < 8; ++mt) {
                float4 fr = *reinterpret_cast<const float4*>(&Fb[cur][16*mt + 4*lg]);
                #pragma unroll
                for (int ct = 0; ct < 4; ++ct) {
                    oacc[mt][ct][0] *= fr.x;
                    oacc[mt][ct][1] *= fr.y;
                    oacc[mt][ct][2] *= fr.z;
                    oacc[mt][ct][3] *= fr.w;
                }
            }
        }

        // ---- PV (fp8): O[m][c] += P[m][s] * V[c][s] ----
        #pragma unroll
        for (int k2 = 0; k2 < 4; ++k2) {
            const int sn = (k2 < 3) ? (s0 + (k2+1)*32) : s0n;
            long vfn[4];
            #pragma unroll
            for (int ct = 0; ct < 4; ++ct)
                vfn[ct] = *reinterpret_cast<const long*>(
                    Vb + (size_t)(ct*16 + lr)*NN + sn + 8*lg);
            long pf[8];
            #pragma unroll
            for (int mt = 0; mt < 8; ++mt)
                pf[mt] = *reinterpret_cast<const long*>(
                    &Plds[cur][(16*mt + lr)*128 + ((k2*32 + 8*lg) ^ pswz)]);
            __builtin_amdgcn_s_setprio(1);
            #pragma unroll
            for (int mt = 0; mt < 8; ++mt)
                #pragma unroll
                for (int ct = 0; ct < 4; ++ct)
                    oacc[mt][ct] = __builtin_amdgcn_mfma_f32_16x16x32_fp8_fp8(
                        pf[mt], vf[ct], oacc[mt][ct], 0, 0, 0);
            __builtin_amdgcn_s_setprio(0);
            #pragma unroll
            for (int ct = 0; ct < 4; ++ct) vf[ct] = vfn[ct];
        }
        cur ^= 1;
    }

    if (lg == 0) Ll[16*wid + lr] = lrun;
    __syncthreads();

    const float alpha = alpha_p[0];
    #pragma unroll
    for (int mt = 0; mt < 8; ++mt) {
        float4 l4 = *reinterpret_cast<const float4*>(&Ll[16*mt + 4*lg]);
        float ar0 = alpha / l4.x, ar1 = alpha / l4.y, ar2 = alpha / l4.z, ar3 = alpha / l4.w;
        #pragma unroll
        for (int ct = 0; ct < 4; ++ct) {
            const int c = 64*wid + 16*ct + lr;
            const size_t base = ((size_t)b*NC + c)*NN + n0 + 16*mt + 4*lg;
            float4 x4 = *reinterpret_cast<const float4*>(x + base);
            float4 o4;
            o4.x = oacc[mt][ct][0] * ar0 + x4.x;
            o4.y = oacc[mt][ct][1] * ar1 + x4.y;
            o4.z = oacc[mt][ct][2] * ar2 + x4.z;
            o4.w = oacc[mt][ct][3] * ar3 + x4.w;
            *reinterpret_cast<float4*>(out + base) = o4;
        }
    }
}

extern "C" void kernel_launch(void* const* d_in, const int* in_sizes, int n_in,
                              void* d_out, int out_size, void* d_ws, size_t ws_size,
                              hipStream_t stream) {
    const float* x     = (const float*)d_in[0];
    const float* wq    = (const float*)d_in[1];
    const float* bq    = (const float*)d_in[2];
    const float* wk    = (const float*)d_in[3];
    const float* bk    = (const float*)d_in[4];
    const float* wv    = (const float*)d_in[5];
    const float* bv    = (const float*)d_in[6];
    const float* alpha = (const float*)d_in[7];

    // ws: QT bf16 4MB | KT bf16 4MB | V fp8 16MB
    unsigned short* QT = (unsigned short*)d_ws;
    unsigned short* KT = QT + (size_t)NB*NN*ND;
    unsigned char*  V  = (unsigned char*)(KT + (size_t)NB*NN*ND);

    dim3 gA(64, 5, 8);
    qkv_proj<<<gA, 256, 0, stream>>>(x, wq, bq, wk, bk, wv, bv, QT, KT, V);
    attn<<<NB * (NN/128), 512, 0, stream>>>(QT, KT, V, x, alpha, (float*)d_out);
}